// Round 2
// baseline (395.804 us; speedup 1.0000x reference)
//
#include <hip/hip_runtime.h>
#include <math.h>

typedef unsigned u32;
typedef _Float16 f16x8 __attribute__((ext_vector_type(8)));
typedef float    f32x16 __attribute__((ext_vector_type(16)));

static __device__ __forceinline__ u32 pack2(_Float16 a, _Float16 b) {
    union { _Float16 h[2]; u32 u; } v;
    v.h[0] = a; v.h[1] = b;
    return v.u;
}

// ws (halves): h1 13,271,040 | A1 129,024 | A2 576,000 | part 8,294,400 | h2 1,658,880
// total 23,929,344 h = 47.9 MB

// ---------------- A-pack: A1[se9][k2 28][lane64][j8] ----------------
__global__ __launch_bounds__(256) void pack_A1v2(
    const float* __restrict__ w1, _Float16* __restrict__ A1)
{
    int i = blockIdx.x * 256 + threadIdx.x;      // 129024 exact
    int j = i & 7;
    int lane = (i >> 3) & 63;
    int t = i >> 9;
    int k2 = t % 28;
    int se = t / 28;                             // 0..8
    int g = lane >> 5, m = lane & 31;
    int tap = 2 * k2 + g;                        // 0..55
    int we = tap / 7, kd = tap % 7;
    float v = 0.f;
    if (m < 30 && j < 7) {
        int dw = m / 15, dh = (m % 15) / 5, oc = m % 5;
        int kh = se - dh, kw = we - dw;
        if (kh >= 0 && kh < 7 && kw >= 0 && kw < 7)
            v = w1[oc * 2401 + kh * 343 + kw * 49 + kd * 7 + j];
    }
    A1[i] = (_Float16)v;
}

// ---------------- A-pack: A2[ci5][she9][k2 25][lane64][j8] ----------------
__global__ __launch_bounds__(256) void pack_A2v2(
    const float* __restrict__ w2, _Float16* __restrict__ A2)
{
    int i = blockIdx.x * 256 + threadIdx.x;      // 576000 exact
    int j = i & 7;
    int lane = (i >> 3) & 63;
    int t = i >> 9;
    int k2 = t % 25; t /= 25;
    int she = t % 9;
    int ci = t / 9;                              // 0..4
    int g = lane >> 5, m = lane & 31;
    int tap = 2 * k2 + g;                        // 0..49
    float v = 0.f;
    if (m < 30 && tap < 49 && j < 7) {
        int dh = m / 10, oc = m % 10;
        int kh = she - dh;
        if (kh >= 0 && kh < 7) {
            int kw = tap / 7, kd = tap % 7;
            v = w2[oc * 12005 + ci * 2401 + kh * 343 + kw * 49 + kd * 7 + j];
        }
    }
    A2[i] = (_Float16)v;
}

// ---------------- conv1: 32x32x16 MFMA, windowed LDS, 4 waves ----------------
// block=(b,OH,OWp): M=30=(dw2,dh3,oc5), N=288=(u2,od12,ot12) -> 9 nt,
// K = 9 se x 28 k2(2 taps x kt8). slab row stride 52 dw.
// A staged in QUARTER buffers (7 k2 = 7KB each, double-buffered):
// LDS 51.8KB -> 3 blocks/CU. Next quarter written from regs DURING compute.
#define C1_SLAB 9360
#define C1_AQ   1792                             // 7 k2 * 64 lanes * 4 u32
__global__ __launch_bounds__(256, 3) void conv1_mfma(
    const float* __restrict__ x, const _Float16* __restrict__ A1,
    const float* __restrict__ b1, _Float16* __restrict__ h1)
{
    __shared__ u32 lds[C1_SLAB + 2 * C1_AQ];     // 51.8 KB
    int tid = threadIdx.x;
    int lane = tid & 63;
    int wave = tid >> 6;
    int col = lane & 31;
    int g = lane >> 5;

    int bid = (int)blockIdx.x;                   // 1536 = 8*192
    int lbid = (bid & 7) * 192 + (bid >> 3);     // XCD chunk swizzle
    int OWp = lbid % 3;
    int OH = (lbid / 3) & 3;
    int b = lbid / 12;

    int qn[3], u_[3], od_[3], ot_[3];
    #pragma unroll
    for (int s = 0; s < 3; ++s) {
        int nt = wave + 4 * s;
        int n = (nt <= 8) ? nt * 32 + col : col;
        int u = n / 144, r2 = n % 144;
        int od = r2 / 12, ot = r2 % 12;
        u_[s] = u; od_[s] = od; ot_[s] = ot;
        qn[s] = (u * 36 + od) * 52 + ot * 4;
    }

    f32x16 acc0, acc1, acc2;
    #pragma unroll
    for (int q = 0; q < 16; ++q) { acc0[q] = 0.f; acc1[q] = 0.f; acc2[q] = 0.f; }

    const float* xbase = x + (size_t)b * 104976;
    const uint4* a1u = (const uint4*)A1;         // quarter Q at offset Q*448
    int w10 = tid / 18, id18 = tid % 18;
    int iw = 4 * OWp + w10;
    bool stager = (tid < 180);

    float2 xr[9];
    uint4 apf[2];
    {   // prologue: x(se=0) and A quarter 0
        if (stager) {
            const float2* src = (const float2*)(xbase + (3 * OH) * 5832 + iw * 324 + id18 * 18);
            #pragma unroll
            for (int q = 0; q < 9; ++q) xr[q] = src[q];
        }
        apf[0] = a1u[tid];
        if (tid < 192) apf[1] = a1u[tid + 256];
    }

    for (int se = 0; se < 9; ++se) {
        __syncthreads();                         // A: prev se compute fully done
        if (stager) {                            // slab write for this se
            _Float16 h[19];
            #pragma unroll
            for (int q = 0; q < 9; ++q) { h[2*q] = (_Float16)xr[q].x; h[2*q+1] = (_Float16)xr[q].y; }
            h[18] = (_Float16)0.f;
            u32 e[9], o[9];
            #pragma unroll
            for (int q = 0; q < 9; ++q) e[q] = pack2(h[2*q], h[2*q+1]);
            #pragma unroll
            for (int q = 0; q < 9; ++q) o[q] = pack2(h[2*q+1], (q < 8) ? h[2*q+2] : h[18]);
            int base = tid * 52;
            #pragma unroll
            for (int ot = 0; ot < 12; ++ot) {
                uint4 w;
                if ((ot & 1) == 0) { const int q = ot >> 1;   w = (uint4){e[q], e[q+1], e[q+2], e[q+3]}; }
                else               { const int q = (ot-1)>>1; w = (uint4){o[q], o[q+1], o[q+2], o[q+3]}; }
                *(uint4*)(&lds[base + ot * 4]) = w;
            }
        }
        {   // write A quarter (se,0) -> buf0  ((se*4)&1 == 0)
            u32* dst = &lds[C1_SLAB];
            *(uint4*)(&dst[tid * 4]) = apf[0];
            if (tid < 192) *(uint4*)(&dst[(tid + 256) * 4]) = apf[1];
        }
        {   // load A quarter (se,1)
            const uint4* src = a1u + (size_t)(se * 4 + 1) * 448;
            apf[0] = src[tid];
            if (tid < 192) apf[1] = src[tid + 256];
        }
        __syncthreads();                         // B: slab + buf0 visible

        if (se < 8 && stager) {                  // prefetch next-se x into regs
            const float2* src = (const float2*)(xbase + (3 * OH + se + 1) * 5832 + iw * 324 + id18 * 18);
            #pragma unroll
            for (int q = 0; q < 9; ++q) xr[q] = src[q];
        }

        #pragma unroll
        for (int q = 0; q < 4; ++q) {            // quarter Q = se*4+q, parity q&1
            if (q) __syncthreads();              // prior quarter's reads done
            if (q < 3) {
                // write apf (quarter Q+1) -> buf[(q+1)&1], then load quarter Q+2
                u32* dst = &lds[C1_SLAB + ((q + 1) & 1) * C1_AQ];
                *(uint4*)(&dst[tid * 4]) = apf[0];
                if (tid < 192) *(uint4*)(&dst[(tid + 256) * 4]) = apf[1];
                int nq = se * 4 + q + 2; if (nq > 35) nq = 35;
                const uint4* src = a1u + (size_t)nq * 448;
                apf[0] = src[tid];
                if (tid < 192) apf[1] = src[tid + 256];
            }
            const u32* alds = &lds[C1_SLAB + (q & 1) * C1_AQ];
            #pragma unroll
            for (int i = 0; i < 7; ++i) {
                const int k2 = q * 7 + i;
                const int t0 = 2 * k2, t1 = 2 * k2 + 1;
                const int c0 = ((t0 / 7) * 18 + (t0 % 7)) * 52;
                const int c1 = ((t1 / 7) * 18 + (t1 % 7)) * 52;
                int qoff = g ? c1 : c0;
                f16x8 af = *(const f16x8*)(alds + (i * 64 + lane) * 4);
                f16x8 bf0 = *(const f16x8*)(lds + qn[0] + qoff);
                f16x8 bf1 = *(const f16x8*)(lds + qn[1] + qoff);
                acc0 = __builtin_amdgcn_mfma_f32_32x32x16_f16(af, bf0, acc0, 0, 0, 0);
                acc1 = __builtin_amdgcn_mfma_f32_32x32x16_f16(af, bf1, acc1, 0, 0, 0);
                if (wave == 0) {
                    f16x8 bf2 = *(const f16x8*)(lds + qn[2] + qoff);
                    acc2 = __builtin_amdgcn_mfma_f32_32x32x16_f16(af, bf2, acc2, 0, 0, 0);
                }
            }
        }
    }

    // store: C row = (r&3)+8*(r>>2)+4*g -> m = dw*15+dh*5+oc; col -> (u,od,ot)
    #pragma unroll
    for (int s = 0; s < 3; ++s) {
        if (s == 2 && wave != 0) continue;
        f32x16 a = (s == 0) ? acc0 : ((s == 1) ? acc1 : acc2);
        int ow_b = 4 * OWp + 2 * u_[s];
        #pragma unroll
        for (int r = 0; r < 16; ++r) {
            const int m0 = (r & 3) + 8 * (r >> 2);
            const int m1 = m0 + 4;
            const int dw0 = m0 / 15, dh0 = (m0 % 15) / 5, oc0 = m0 % 5;
            const int dw1 = m1 / 15, dh1 = (m1 % 15) / 5, oc1 = m1 % 5;
            if (m1 >= 30 && g) continue;
            int dw = g ? dw1 : dw0;
            int dh = g ? dh1 : dh0;
            int oc = g ? oc1 : oc0;
            float bv = g ? b1[oc1] : b1[oc0];
            float v = fmaxf(a[r] + bv, 0.f);
            h1[(size_t)b * 103680 + oc * 20736 + (3 * OH + dh) * 1728
               + (ow_b + dw) * 144 + od_[s] * 12 + ot_[s]] = (_Float16)v;
        }
    }
}

// ---------------- conv2: 32x32x16 MFMA, windowed LDS, ci-split ----------------
// block=(b,OH2,ci): M=30=(dh3,oc10), N=216 -> 7 nt, K = 9 she x 25 k2.
// A staged in CHUNK buffers (5 k2 = 5KB, double-buffered): LDS 26.4KB -> 5 blocks/CU.
#define C2_SLAB 4032
#define C2_AQ   1280                             // 5 k2 * 64 lanes * 4 u32
__global__ __launch_bounds__(256, 5) void conv2_mfma(
    const _Float16* __restrict__ h1, const _Float16* __restrict__ A2,
    _Float16* __restrict__ part)
{
    __shared__ u32 lds[C2_SLAB + 2 * C2_AQ];     // 26.4 KB
    int tid = threadIdx.x;
    int lane = tid & 63;
    int wave = tid >> 6;
    int col = lane & 31;
    int g = lane >> 5;

    int bid = (int)blockIdx.x;                   // 1280 = 8*160
    int lbid = (bid & 7) * 160 + (bid >> 3);
    int ci = lbid % 5;
    int OH2 = (lbid / 5) & 1;
    int b = lbid / 10;

    int qn[2], n_[2];
    #pragma unroll
    for (int s = 0; s < 2; ++s) {
        int nt = wave + 4 * s;
        int n = nt * 32 + col;                   // nt<=6 -> n<224
        n_[s] = n;
        int nc = (n < 216) ? n : 215;
        int ow = nc / 36, rem = nc % 36;
        int od = rem / 6, ot = rem % 6;
        qn[s] = (ow * 12 + od) * 28 + ot * 4;
    }

    f32x16 acc0, acc1;
    #pragma unroll
    for (int q = 0; q < 16; ++q) { acc0[q] = 0.f; acc1[q] = 0.f; }

    const _Float16* hbase = h1 + (size_t)b * 103680 + ci * 20736;
    const uint4* a2u = (const uint4*)(A2 + ((size_t)ci * 9) * 12800); // chunk C at C*320
    int iw = tid / 12, id12 = tid % 12;
    bool stager = (tid < 144);

    uint2 xr[3];
    uint4 apf[2];
    {
        if (stager) {
            const uint2* src = (const uint2*)(hbase + (3 * OH2) * 1728 + iw * 144 + id12 * 12);
            #pragma unroll
            for (int q = 0; q < 3; ++q) xr[q] = src[q];
        }
        apf[0] = a2u[tid];
        if (tid < 64) apf[1] = a2u[tid + 256];
    }

    for (int she = 0; she < 9; ++she) {
        int pse = she & 1;                       // parity of chunk C = she*5
        __syncthreads();                         // A: prev she compute done
        if (stager) {
            _Float16 h[14];
            *(uint2*)&h[0] = xr[0]; *(uint2*)&h[4] = xr[1]; *(uint2*)&h[8] = xr[2];
            h[12] = (_Float16)0.f;
            u32 e[6], o[6];
            #pragma unroll
            for (int q = 0; q < 6; ++q) e[q] = pack2(h[2*q], h[2*q+1]);
            #pragma unroll
            for (int q = 0; q < 6; ++q) o[q] = pack2(h[2*q+1], (q < 5) ? h[2*q+2] : h[12]);
            int base = tid * 28;
            #pragma unroll
            for (int ot = 0; ot < 6; ++ot) {
                uint4 w;
                if ((ot & 1) == 0) { const int q = ot >> 1;   w = (uint4){e[q], e[q+1], e[q+2], e[q+3]}; }
                else               { const int q = (ot-1)>>1; w = (uint4){o[q], o[q+1], o[q+2], o[q+3]}; }
                *(uint4*)(&lds[base + ot * 4]) = w;
            }
        }
        {   // write chunk (she,0) -> buf[pse]
            u32* dst = &lds[C2_SLAB + pse * C2_AQ];
            *(uint4*)(&dst[tid * 4]) = apf[0];
            if (tid < 64) *(uint4*)(&dst[(tid + 256) * 4]) = apf[1];
        }
        {   // load chunk (she,1)
            const uint4* src = a2u + (size_t)(she * 5 + 1) * 320;
            apf[0] = src[tid];
            if (tid < 64) apf[1] = src[tid + 256];
        }
        __syncthreads();                         // B

        if (she < 8 && stager) {
            const uint2* src = (const uint2*)(hbase + (3 * OH2 + she + 1) * 1728 + iw * 144 + id12 * 12);
            #pragma unroll
            for (int q = 0; q < 3; ++q) xr[q] = src[q];
        }

        #pragma unroll
        for (int c = 0; c < 5; ++c) {            // chunk C = she*5+c, parity (she+c)&1
            if (c) __syncthreads();
            int pc = (she + c) & 1;
            if (c < 4) {
                u32* dst = &lds[C2_SLAB + (pc ^ 1) * C2_AQ];
                *(uint4*)(&dst[tid * 4]) = apf[0];
                if (tid < 64) *(uint4*)(&dst[(tid + 256) * 4]) = apf[1];
                int nq = she * 5 + c + 2; if (nq > 44) nq = 44;
                const uint4* src = a2u + (size_t)nq * 320;
                apf[0] = src[tid];
                if (tid < 64) apf[1] = src[tid + 256];
            }
            const u32* alds = &lds[C2_SLAB + pc * C2_AQ];
            #pragma unroll
            for (int i = 0; i < 5; ++i) {
                const int k2 = c * 5 + i;
                const int t0 = 2 * k2, t1 = 2 * k2 + 1;
                const int c0 = ((t0 / 7) * 12 + (t0 % 7)) * 28;
                const int c1 = (t1 < 49) ? (((t1 / 7) * 12 + (t1 % 7)) * 28) : 0;
                int qoff = g ? c1 : c0;
                f16x8 af = *(const f16x8*)(alds + (i * 64 + lane) * 4);
                f16x8 bf0 = *(const f16x8*)(lds + qn[0] + qoff);
                acc0 = __builtin_amdgcn_mfma_f32_32x32x16_f16(af, bf0, acc0, 0, 0, 0);
                if (wave < 3) {
                    f16x8 bf1 = *(const f16x8*)(lds + qn[1] + qoff);
                    acc1 = __builtin_amdgcn_mfma_f32_32x32x16_f16(af, bf1, acc1, 0, 0, 0);
                }
            }
        }
    }

    // store partials: part[ci][b*6+oh][oc][216]; m = dh*10+oc
    #pragma unroll
    for (int s = 0; s < 2; ++s) {
        if (s == 1 && wave >= 3) continue;
        if (n_[s] >= 216) continue;
        f32x16 a = (s == 0) ? acc0 : acc1;
        #pragma unroll
        for (int r = 0; r < 16; ++r) {
            const int m0 = (r & 3) + 8 * (r >> 2);
            const int m1 = m0 + 4;
            const int dh0 = m0 / 10, oc0 = m0 % 10;
            const int dh1 = m1 / 10, oc1 = m1 % 10;
            if (m1 >= 30 && g) continue;
            int dh = g ? dh1 : dh0;
            int oc = g ? oc1 : oc0;
            int oh = 3 * OH2 + dh;
            part[((size_t)(ci * 768 + b * 6 + oh) * 10 + oc) * 216 + n_[s]] = (_Float16)a[r];
        }
    }
}

// ---------------- reduce 5 ci-partials + bias + ReLU -> h2 ----------------
__global__ __launch_bounds__(256) void conv2_reduce(
    const _Float16* __restrict__ part, const float* __restrict__ b2,
    _Float16* __restrict__ h2)
{
    int flat = blockIdx.x * 256 + threadIdx.x;   // 1,658,880 exact
    int n_loc = flat % 216;
    int t = flat / 216;
    int oc = t % 10;  t /= 10;
    int oh = t % 6;
    int b  = t / 6;
    float s = 0.f;
    #pragma unroll
    for (int ci = 0; ci < 5; ++ci)
        s += (float)part[((size_t)(ci * 768 + b * 6 + oh) * 10 + oc) * 216 + n_loc];
    s = fmaxf(s + b2[oc], 0.f);
    h2[(size_t)b * 12960 + oc * 1296 + oh * 216 + n_loc] = (_Float16)s;
}

// ---------------- linear + sigmoid ----------------
__global__ __launch_bounds__(256) void linear_kernel(
    const _Float16* __restrict__ h2, const float* __restrict__ wl,
    const float* __restrict__ bl, float* __restrict__ out)
{
    int b = blockIdx.x;
    const _Float16* hb = h2 + (size_t)b * 12960;
    float s = 0.f;
    for (int i = threadIdx.x; i < 12960; i += 256)
        s += (float)hb[i] * wl[i];
    #pragma unroll
    for (int off = 32; off > 0; off >>= 1)
        s += __shfl_down(s, off, 64);
    __shared__ float wsum[4];
    int wave = threadIdx.x >> 6;
    if ((threadIdx.x & 63) == 0) wsum[wave] = s;
    __syncthreads();
    if (threadIdx.x == 0) {
        float tot = wsum[0] + wsum[1] + wsum[2] + wsum[3] + bl[0];
        out[b] = 1.f / (1.f + expf(-tot));
    }
}

extern "C" void kernel_launch(void* const* d_in, const int* in_sizes, int n_in,
                              void* d_out, int out_size, void* d_ws, size_t ws_size,
                              hipStream_t stream) {
    const float* x  = (const float*)d_in[0];
    const float* w1 = (const float*)d_in[1];
    const float* b1 = (const float*)d_in[2];
    const float* w2 = (const float*)d_in[3];
    const float* b2 = (const float*)d_in[4];
    const float* wl = (const float*)d_in[5];
    const float* bl = (const float*)d_in[6];
    float* out = (float*)d_out;

    _Float16* h1   = (_Float16*)d_ws;            // 13,271,040
    _Float16* A1   = h1 + 13271040;              //    129,024
    _Float16* A2   = A1 + 129024;                //    576,000
    _Float16* part = A2 + 576000;                //  8,294,400
    _Float16* h2   = part + 8294400;             //  1,658,880

    pack_A1v2<<<504, 256, 0, stream>>>(w1, A1);
    pack_A2v2<<<2250, 256, 0, stream>>>(w2, A2);
    conv1_mfma<<<1536, 256, 0, stream>>>(x, A1, b1, h1);
    conv2_mfma<<<1280, 256, 0, stream>>>(h1, A2, part);
    conv2_reduce<<<6480, 256, 0, stream>>>(part, b2, h2);
    linear_kernel<<<128, 256, 0, stream>>>(h2, wl, bl, out);
}

// Round 3
// 345.968 us; speedup vs baseline: 1.1440x; 1.1440x over previous
//
#include <hip/hip_runtime.h>
#include <math.h>

typedef unsigned u32;
typedef _Float16 f16x8 __attribute__((ext_vector_type(8)));
typedef float    f32x16 __attribute__((ext_vector_type(16)));

static __device__ __forceinline__ u32 pack2(_Float16 a, _Float16 b) {
    union { _Float16 h[2]; u32 u; } v;
    v.h[0] = a; v.h[1] = b;
    return v.u;
}

// ws (halves): h1 13,271,040 | A1 129,024 | A2 576,000 | part 8,294,400 | h2 1,658,880
// total 23,929,344 h = 47.9 MB

// ---------------- A-pack: A1[se9][k2 28][lane64][j8] ----------------
__global__ __launch_bounds__(256) void pack_A1v2(
    const float* __restrict__ w1, _Float16* __restrict__ A1)
{
    int i = blockIdx.x * 256 + threadIdx.x;      // 129024 exact
    int j = i & 7;
    int lane = (i >> 3) & 63;
    int t = i >> 9;
    int k2 = t % 28;
    int se = t / 28;                             // 0..8
    int g = lane >> 5, m = lane & 31;
    int tap = 2 * k2 + g;                        // 0..55
    int we = tap / 7, kd = tap % 7;
    float v = 0.f;
    if (m < 30 && j < 7) {
        int dw = m / 15, dh = (m % 15) / 5, oc = m % 5;
        int kh = se - dh, kw = we - dw;
        if (kh >= 0 && kh < 7 && kw >= 0 && kw < 7)
            v = w1[oc * 2401 + kh * 343 + kw * 49 + kd * 7 + j];
    }
    A1[i] = (_Float16)v;
}

// ---------------- A-pack: A2[ci5][she9][k2 25][lane64][j8] ----------------
__global__ __launch_bounds__(256) void pack_A2v2(
    const float* __restrict__ w2, _Float16* __restrict__ A2)
{
    int i = blockIdx.x * 256 + threadIdx.x;      // 576000 exact
    int j = i & 7;
    int lane = (i >> 3) & 63;
    int t = i >> 9;
    int k2 = t % 25; t /= 25;
    int she = t % 9;
    int ci = t / 9;                              // 0..4
    int g = lane >> 5, m = lane & 31;
    int tap = 2 * k2 + g;                        // 0..49
    float v = 0.f;
    if (m < 30 && tap < 49 && j < 7) {
        int dh = m / 10, oc = m % 10;
        int kh = she - dh;
        if (kh >= 0 && kh < 7) {
            int kw = tap / 7, kd = tap % 7;
            v = w2[oc * 12005 + ci * 2401 + kh * 343 + kw * 49 + kd * 7 + j];
        }
    }
    A2[i] = (_Float16)v;
}

// ---------------- conv1: 32x32x16 MFMA, windowed LDS, 4 waves ----------------
// block=(b,OH,OWp): M=30=(dw2,dh3,oc5), N=288=(u2,od12,ot12) -> 9 nt,
// K = 9 se x 28 k2(2 taps x kt8). slab row stride 52 dw (bank-perfect).
// Hybrid wave split: wave w = (h=w&1: nt-half, kp=w>>1: K-half).
//   h=0 -> tiles 0..4, h=1 -> tiles 5..8; kp window = k2 in [14*kp, 14*kp+14).
//   Per k2: 1 A-read serves 4-5 MFMAs (A-dup 4x->2x), 4-5 indep acc chains.
// Epilogue: pair (w, w^2) sums partials via LDS; kp=0 stores r0..7, kp=1 r8..15.
#define C1_SLAB 9360
#define C1_ALDS 7168
__global__ __launch_bounds__(256, 2) void conv1_mfma(
    const float* __restrict__ x, const _Float16* __restrict__ A1,
    const float* __restrict__ b1, _Float16* __restrict__ h1)
{
    __shared__ u32 lds[C1_SLAB + C1_ALDS];       // 66.1 KB
    int tid = threadIdx.x;
    int lane = tid & 63;
    int wave = tid >> 6;
    int col = lane & 31;
    int g = lane >> 5;
    int h  = wave & 1;                           // nt-half
    int kp = wave >> 1;                          // K-half

    int bid = (int)blockIdx.x;                   // 1536 = 8*192
    int lbid = (bid & 7) * 192 + (bid >> 3);     // XCD chunk swizzle
    int OWp = lbid % 3;
    int OH = (lbid / 3) & 3;
    int b = lbid / 12;

    int qn[5];
    #pragma unroll
    for (int j = 0; j < 5; ++j) {
        int tile = h ? ((j < 4) ? 5 + j : 8) : j;   // h=1,j=4 is a dummy (unused)
        int n = tile * 32 + col;
        int u = n / 144, r2 = n % 144;
        int od = r2 / 12, ot = r2 % 12;
        qn[j] = (u * 36 + od) * 52 + ot * 4;
    }

    f32x16 acc[5];
    #pragma unroll
    for (int j = 0; j < 5; ++j)
        #pragma unroll
        for (int q = 0; q < 16; ++q) acc[j][q] = 0.f;

    const float* xbase = x + (size_t)b * 104976;
    const uint4* a1u = (const uint4*)A1;
    int w10 = tid / 18, id18 = tid % 18;
    int iw = 4 * OWp + w10;
    bool stager = (tid < 180);

    int kb    = kp * 14;                         // k2 window base
    int wkoff = kp * 3744;                       // = kp*72*52 (qoff base)

    float2 xr[9]; uint4 apf[7];
    {   // preload se=0
        if (stager) {
            const float2* src = (const float2*)(xbase + (3 * OH) * 5832 + iw * 324 + id18 * 18);
            #pragma unroll
            for (int q = 0; q < 9; ++q) xr[q] = src[q];
        }
        #pragma unroll
        for (int i = 0; i < 7; ++i) apf[i] = a1u[tid + 256 * i];
    }

    for (int se = 0; se < 9; ++se) {
        __syncthreads();                         // prior compute done
        if (stager) {
            _Float16 hh[19];
            #pragma unroll
            for (int q = 0; q < 9; ++q) { hh[2*q] = (_Float16)xr[q].x; hh[2*q+1] = (_Float16)xr[q].y; }
            hh[18] = (_Float16)0.f;
            u32 e[9], o[9];
            #pragma unroll
            for (int q = 0; q < 9; ++q) e[q] = pack2(hh[2*q], hh[2*q+1]);
            #pragma unroll
            for (int q = 0; q < 9; ++q) o[q] = pack2(hh[2*q+1], (q < 8) ? hh[2*q+2] : hh[18]);
            int base = tid * 52;
            #pragma unroll
            for (int ot = 0; ot < 12; ++ot) {
                uint4 w;
                if ((ot & 1) == 0) { const int q = ot >> 1;   w = (uint4){e[q], e[q+1], e[q+2], e[q+3]}; }
                else               { const int q = (ot-1)>>1; w = (uint4){o[q], o[q+1], o[q+2], o[q+3]}; }
                *(uint4*)(&lds[base + ot * 4]) = w;
            }
        }
        {
            uint4* adst = (uint4*)(&lds[C1_SLAB]);
            #pragma unroll
            for (int i = 0; i < 7; ++i) adst[tid + 256 * i] = apf[i];
        }
        __syncthreads();

        if (se < 8) {                            // prefetch next stage into regs
            if (stager) {
                const float2* src = (const float2*)(xbase + (3 * OH + se + 1) * 5832 + iw * 324 + id18 * 18);
                #pragma unroll
                for (int q = 0; q < 9; ++q) xr[q] = src[q];
            }
            const uint4* asrc = a1u + (size_t)(se + 1) * 1792;
            #pragma unroll
            for (int i = 0; i < 7; ++i) apf[i] = asrc[tid + 256 * i];
        }

        const u32* aptr = &lds[C1_SLAB] + kb * 256 + lane * 4;
        #pragma unroll
        for (int i = 0; i < 14; ++i) {           // k2 = kb + i
            const int t0 = 2 * i, t1 = 2 * i + 1;
            const int c0s = ((t0 / 7) * 18 + (t0 % 7)) * 52;
            const int c1s = ((t1 / 7) * 18 + (t1 % 7)) * 52;
            int qoff = wkoff + (g ? c1s : c0s);
            f16x8 af = *(const f16x8*)(aptr + i * 256);
            f16x8 bf0 = *(const f16x8*)(lds + qn[0] + qoff);
            f16x8 bf1 = *(const f16x8*)(lds + qn[1] + qoff);
            f16x8 bf2 = *(const f16x8*)(lds + qn[2] + qoff);
            f16x8 bf3 = *(const f16x8*)(lds + qn[3] + qoff);
            acc[0] = __builtin_amdgcn_mfma_f32_32x32x16_f16(af, bf0, acc[0], 0, 0, 0);
            acc[1] = __builtin_amdgcn_mfma_f32_32x32x16_f16(af, bf1, acc[1], 0, 0, 0);
            acc[2] = __builtin_amdgcn_mfma_f32_32x32x16_f16(af, bf2, acc[2], 0, 0, 0);
            acc[3] = __builtin_amdgcn_mfma_f32_32x32x16_f16(af, bf3, acc[3], 0, 0, 0);
            if (h == 0) {
                f16x8 bf4 = *(const f16x8*)(lds + qn[4] + qoff);
                acc[4] = __builtin_amdgcn_mfma_f32_32x32x16_f16(af, bf4, acc[4], 0, 0, 0);
            }
        }
    }

    // ---- epilogue: pair-reduce (w <-> w^2) + bias + ReLU + store ----
    // kp=0 stores rows r=0..7 (writes r=8..15 to LDS); kp=1 stores r=8..15.
    // region for (j3, h): 1024 f32 at lds[(j3*2+h)*1024], both pair-waves write
    // disjoint halves. Round 0: j=0..2; round 1: j=3..4 (h=0) / j=3 (h=1).
    __syncthreads();                             // all compute done, slab free
    int ow_base = 4 * OWp;
    #pragma unroll
    for (int rnd = 0; rnd < 2; ++rnd) {
        #pragma unroll
        for (int j3 = 0; j3 < 3; ++j3) {         // write non-stored half
            const int j = rnd * 3 + j3;
            if (j > 4) continue;
            if (h && j == 4) continue;
            float* reg = (float*)&lds[(j3 * 2 + h) * 1024];
            #pragma unroll
            for (int q = 0; q < 8; ++q) {
                int rw = kp ? q : q + 8;
                reg[rw * 64 + lane] = kp ? acc[j][q] : acc[j][q + 8];
            }
        }
        __syncthreads();
        #pragma unroll
        for (int j3 = 0; j3 < 3; ++j3) {         // read partner half + store
            const int j = rnd * 3 + j3;
            if (j > 4) continue;
            if (h && j == 4) continue;
            const float* reg = (const float*)&lds[(j3 * 2 + h) * 1024];
            int tile = h ? 5 + j : j;
            int n = tile * 32 + col;
            int u = n / 144, r2 = n % 144;
            int od = r2 / 12, ot = r2 % 12;
            int ow_b = ow_base + 2 * u;
            #pragma unroll
            for (int q = 0; q < 8; ++q) {
                int m = (q & 3) + 8 * (q >> 2) + 16 * kp + 4 * g;
                if (m >= 30) continue;           // only kp=1,g=1,q=6,7
                int rs = kp ? q + 8 : q;
                float own = kp ? acc[j][q + 8] : acc[j][q];
                float sum = own + reg[rs * 64 + lane];
                int dw = m / 15, dh = (m % 15) / 5, oc = m % 5;
                float v = fmaxf(sum + b1[oc], 0.f);
                h1[(size_t)b * 103680 + oc * 20736 + (3 * OH + dh) * 1728
                   + (ow_b + dw) * 144 + od * 12 + ot] = (_Float16)v;
            }
        }
        __syncthreads();
    }
}

// ---------------- conv2: 32x32x16 MFMA, windowed LDS, ci-split ----------------
// block=(b,OH2,ci): M=30=(dh3,oc10), N=216 -> 7 nt, K = 9 she x 25 k2.
#define C2_SLAB 4032
#define C2_ALDS 6400
__global__ __launch_bounds__(256, 3) void conv2_mfma(
    const _Float16* __restrict__ h1, const _Float16* __restrict__ A2,
    _Float16* __restrict__ part)
{
    __shared__ u32 lds[C2_SLAB + C2_ALDS];       // 41.7 KB
    int tid = threadIdx.x;
    int lane = tid & 63;
    int wave = tid >> 6;
    int col = lane & 31;
    int g = lane >> 5;

    int bid = (int)blockIdx.x;                   // 1280 = 8*160
    int lbid = (bid & 7) * 160 + (bid >> 3);
    int ci = lbid % 5;
    int OH2 = (lbid / 5) & 1;
    int b = lbid / 10;

    int qn[2], n_[2];
    #pragma unroll
    for (int s = 0; s < 2; ++s) {
        int nt = wave + 4 * s;
        int n = nt * 32 + col;                   // nt<=6 -> n<224
        n_[s] = n;
        int nc = (n < 216) ? n : 215;
        int ow = nc / 36, rem = nc % 36;
        int od = rem / 6, ot = rem % 6;
        qn[s] = (ow * 12 + od) * 28 + ot * 4;
    }

    f32x16 acc0, acc1;
    #pragma unroll
    for (int q = 0; q < 16; ++q) { acc0[q] = 0.f; acc1[q] = 0.f; }

    const _Float16* hbase = h1 + (size_t)b * 103680 + ci * 20736;
    const uint4* a2u = (const uint4*)(A2 + ((size_t)ci * 9) * 12800);
    int iw = tid / 12, id12 = tid % 12;
    bool stager = (tid < 144);

    uint2 xr[3]; uint4 apf[7];
    {
        if (stager) {
            const uint2* src = (const uint2*)(hbase + (3 * OH2) * 1728 + iw * 144 + id12 * 12);
            #pragma unroll
            for (int q = 0; q < 3; ++q) xr[q] = src[q];
        }
        #pragma unroll
        for (int i = 0; i < 7; ++i) { int q = tid + 256 * i; if (q < 1600) apf[i] = a2u[q]; }
    }

    for (int she = 0; she < 9; ++she) {
        __syncthreads();
        if (stager) {
            _Float16 h[14];
            *(uint2*)&h[0] = xr[0]; *(uint2*)&h[4] = xr[1]; *(uint2*)&h[8] = xr[2];
            h[12] = (_Float16)0.f;
            u32 e[6], o[6];
            #pragma unroll
            for (int q = 0; q < 6; ++q) e[q] = pack2(h[2*q], h[2*q+1]);
            #pragma unroll
            for (int q = 0; q < 6; ++q) o[q] = pack2(h[2*q+1], (q < 5) ? h[2*q+2] : h[12]);
            int base = tid * 28;
            #pragma unroll
            for (int ot = 0; ot < 6; ++ot) {
                uint4 w;
                if ((ot & 1) == 0) { const int q = ot >> 1;   w = (uint4){e[q], e[q+1], e[q+2], e[q+3]}; }
                else               { const int q = (ot-1)>>1; w = (uint4){o[q], o[q+1], o[q+2], o[q+3]}; }
                *(uint4*)(&lds[base + ot * 4]) = w;
            }
        }
        {
            uint4* adst = (uint4*)(&lds[C2_SLAB]);
            #pragma unroll
            for (int i = 0; i < 7; ++i) { int q = tid + 256 * i; if (q < 1600) adst[q] = apf[i]; }
        }
        __syncthreads();

        if (she < 8) {
            if (stager) {
                const uint2* src = (const uint2*)(hbase + (3 * OH2 + she + 1) * 1728 + iw * 144 + id12 * 12);
                #pragma unroll
                for (int q = 0; q < 3; ++q) xr[q] = src[q];
            }
            const uint4* asrc = a2u + (size_t)(she + 1) * 1600;
            #pragma unroll
            for (int i = 0; i < 7; ++i) { int q = tid + 256 * i; if (q < 1600) apf[i] = asrc[q]; }
        }

        const u32* alds = &lds[C2_SLAB];
        #pragma unroll
        for (int k2 = 0; k2 < 25; ++k2) {
            const int t0 = 2 * k2, t1 = 2 * k2 + 1;
            const int c0 = ((t0 / 7) * 12 + (t0 % 7)) * 28;
            const int c1 = (t1 < 49) ? ((t1 / 7) * 12 + (t1 % 7)) * 28 : 0;
            int qoff = g ? c1 : c0;
            f16x8 af = *(const f16x8*)(alds + (k2 * 64 + lane) * 4);
            f16x8 bf0 = *(const f16x8*)(lds + qn[0] + qoff);
            acc0 = __builtin_amdgcn_mfma_f32_32x32x16_f16(af, bf0, acc0, 0, 0, 0);
            if (wave < 3) {
                f16x8 bf1 = *(const f16x8*)(lds + qn[1] + qoff);
                acc1 = __builtin_amdgcn_mfma_f32_32x32x16_f16(af, bf1, acc1, 0, 0, 0);
            }
        }
    }

    // store partials: part[ci][b*6+oh][oc][216]; m = dh*10+oc
    #pragma unroll
    for (int s = 0; s < 2; ++s) {
        if (s == 1 && wave >= 3) continue;
        if (n_[s] >= 216) continue;
        f32x16 a = (s == 0) ? acc0 : acc1;
        #pragma unroll
        for (int r = 0; r < 16; ++r) {
            const int m0 = (r & 3) + 8 * (r >> 2);
            const int m1 = m0 + 4;
            const int dh0 = m0 / 10, oc0 = m0 % 10;
            const int dh1 = m1 / 10, oc1 = m1 % 10;
            if (m1 >= 30 && g) continue;
            int dh = g ? dh1 : dh0;
            int oc = g ? oc1 : oc0;
            int oh = 3 * OH2 + dh;
            part[((size_t)(ci * 768 + b * 6 + oh) * 10 + oc) * 216 + n_[s]] = (_Float16)a[r];
        }
    }
}

// ---------------- reduce 5 ci-partials + bias + ReLU -> h2 ----------------
__global__ __launch_bounds__(256) void conv2_reduce(
    const _Float16* __restrict__ part, const float* __restrict__ b2,
    _Float16* __restrict__ h2)
{
    int flat = blockIdx.x * 256 + threadIdx.x;   // 1,658,880 exact
    int n_loc = flat % 216;
    int t = flat / 216;
    int oc = t % 10;  t /= 10;
    int oh = t % 6;
    int b  = t / 6;
    float s = 0.f;
    #pragma unroll
    for (int ci = 0; ci < 5; ++ci)
        s += (float)part[((size_t)(ci * 768 + b * 6 + oh) * 10 + oc) * 216 + n_loc];
    s = fmaxf(s + b2[oc], 0.f);
    h2[(size_t)b * 12960 + oc * 1296 + oh * 216 + n_loc] = (_Float16)s;
}

// ---------------- linear + sigmoid ----------------
__global__ __launch_bounds__(256) void linear_kernel(
    const _Float16* __restrict__ h2, const float* __restrict__ wl,
    const float* __restrict__ bl, float* __restrict__ out)
{
    int b = blockIdx.x;
    const _Float16* hb = h2 + (size_t)b * 12960;
    float s = 0.f;
    for (int i = threadIdx.x; i < 12960; i += 256)
        s += (float)hb[i] * wl[i];
    #pragma unroll
    for (int off = 32; off > 0; off >>= 1)
        s += __shfl_down(s, off, 64);
    __shared__ float wsum[4];
    int wave = threadIdx.x >> 6;
    if ((threadIdx.x & 63) == 0) wsum[wave] = s;
    __syncthreads();
    if (threadIdx.x == 0) {
        float tot = wsum[0] + wsum[1] + wsum[2] + wsum[3] + bl[0];
        out[b] = 1.f / (1.f + expf(-tot));
    }
}

extern "C" void kernel_launch(void* const* d_in, const int* in_sizes, int n_in,
                              void* d_out, int out_size, void* d_ws, size_t ws_size,
                              hipStream_t stream) {
    const float* x  = (const float*)d_in[0];
    const float* w1 = (const float*)d_in[1];
    const float* b1 = (const float*)d_in[2];
    const float* w2 = (const float*)d_in[3];
    const float* b2 = (const float*)d_in[4];
    const float* wl = (const float*)d_in[5];
    const float* bl = (const float*)d_in[6];
    float* out = (float*)d_out;

    _Float16* h1   = (_Float16*)d_ws;            // 13,271,040
    _Float16* A1   = h1 + 13271040;              //    129,024
    _Float16* A2   = A1 + 129024;                //    576,000
    _Float16* part = A2 + 576000;                //  8,294,400
    _Float16* h2   = part + 8294400;             //  1,658,880

    pack_A1v2<<<504, 256, 0, stream>>>(w1, A1);
    pack_A2v2<<<2250, 256, 0, stream>>>(w2, A2);
    conv1_mfma<<<1536, 256, 0, stream>>>(x, A1, b1, h1);
    conv2_mfma<<<1280, 256, 0, stream>>>(h1, A2, part);
    conv2_reduce<<<6480, 256, 0, stream>>>(part, b2, h2);
    linear_kernel<<<128, 256, 0, stream>>>(h2, wl, bl, out);
}

// Round 4
// 320.215 us; speedup vs baseline: 1.2361x; 1.0804x over previous
//
#include <hip/hip_runtime.h>
#include <math.h>

typedef unsigned u32;
typedef _Float16 f16x8 __attribute__((ext_vector_type(8)));
typedef float    f32x16 __attribute__((ext_vector_type(16)));

static __device__ __forceinline__ u32 pack2(_Float16 a, _Float16 b) {
    union { _Float16 h[2]; u32 u; } v;
    v.h[0] = a; v.h[1] = b;
    return v.u;
}

// ws (halves): h1 13,271,040 | A1 129,024 (13,720 used) | A2 576,000 | part 8,294,400 | h2 1,658,880

// ---------------- A-pack: A1'[kh7][kw7][kd7][oc5][j8] ----------------
// Persistent gather table: entry = w1[oc][kh][kw][kd][j<7], j=7 -> 0.
__global__ __launch_bounds__(256) void pack_A1p(
    const float* __restrict__ w1, _Float16* __restrict__ A1)
{
    int i = blockIdx.x * 256 + threadIdx.x;      // 13720 (grid 54, guarded)
    if (i >= 13720) return;
    int j = i & 7;
    int t = i >> 3;
    int oc = t % 5; t /= 5;
    int kd = t % 7; t /= 7;
    int kw = t % 7;
    int kh = t / 7;
    float v = (j < 7) ? w1[oc * 2401 + kh * 343 + kw * 49 + kd * 7 + j] : 0.f;
    A1[i] = (_Float16)v;
}

// ---------------- A-pack: A2[ci5][she9][k2 25][lane64][j8] ----------------
__global__ __launch_bounds__(256) void pack_A2v2(
    const float* __restrict__ w2, _Float16* __restrict__ A2)
{
    int i = blockIdx.x * 256 + threadIdx.x;      // 576000 exact
    int j = i & 7;
    int lane = (i >> 3) & 63;
    int t = i >> 9;
    int k2 = t % 25; t /= 25;
    int she = t % 9;
    int ci = t / 9;                              // 0..4
    int g = lane >> 5, m = lane & 31;
    int tap = 2 * k2 + g;                        // 0..49
    float v = 0.f;
    if (m < 30 && tap < 49 && j < 7) {
        int dh = m / 10, oc = m % 10;
        int kh = she - dh;
        if (kh >= 0 && kh < 7) {
            int kw = tap / 7, kd = tap % 7;
            v = w2[oc * 12005 + ci * 2401 + kh * 343 + kw * 49 + kd * 7 + j];
        }
    }
    A2[i] = (_Float16)v;
}

// ---------------- conv1: 32x32x16 MFMA, windowed LDS, 4 waves ----------------
// block=(b,OH,OWp): M=30=(dw2,dh3,oc5), N=288=(u2,od12,ot12) -> 9 nt,
// K = 9 se x 28 k2(2 taps x kt8). slab row stride 52 dw.
// A via persistent LDS gather table A'[kh][kw][kd][oc][j8]:
//   lane addr = C1_AOFF + kh*980 + oc*4 + 20g - 140dw + 40*k2  (linear in k2!)
//   kh/kw-invalid lanes -> zero range (reads lds[ZOFF+40k2], zeros).
// Per-se staging = slab only (A never re-staged).
#define C1_SLAB 9360
#define C1_AOFF 9360
#define C1_ZOFF (9360 + 6860)
#define C1_LDS  (9360 + 6860 + 1084)             // 69.2 KB
__global__ __launch_bounds__(256, 2) void conv1_mfma(
    const float* __restrict__ x, const _Float16* __restrict__ A1,
    const float* __restrict__ b1, _Float16* __restrict__ h1)
{
    __shared__ u32 lds[C1_LDS];
    int tid = threadIdx.x;
    int lane = tid & 63;
    int wave = tid >> 6;
    int col = lane & 31;
    int g = lane >> 5;

    int bid = (int)blockIdx.x;                   // 1536 = 8*192
    int lbid = (bid & 7) * 192 + (bid >> 3);     // XCD chunk swizzle
    int OWp = lbid % 3;
    int OH = (lbid / 3) & 3;
    int b = lbid / 12;

    int qn[3], u_[3], od_[3], ot_[3];
    #pragma unroll
    for (int s = 0; s < 3; ++s) {
        int nt = wave + 4 * s;
        int n = (nt <= 8) ? nt * 32 + col : col;
        int u = n / 144, r2 = n % 144;
        int od = r2 / 12, ot = r2 % 12;
        u_[s] = u; od_[s] = od; ot_[s] = ot;
        qn[s] = (u * 36 + od) * 52 + ot * 4;
    }

    f32x16 acc0, acc1, acc2;
    #pragma unroll
    for (int q = 0; q < 16; ++q) { acc0[q] = 0.f; acc1[q] = 0.f; acc2[q] = 0.f; }

    const float* xbase = x + (size_t)b * 104976;
    int w10 = tid / 18, id18 = tid % 18;
    int iw = 4 * OWp + w10;
    bool stager = (tid < 180);

    // lane A-gather constants (m = col: dw2, dh3, oc5; m>=30 reads junk, rows discarded)
    int am_dw = col / 15, am_dh = (col % 15) / 5, am_oc = col % 5;
    int alane = am_oc * 4 + 20 * g - 140 * am_dw;
    bool eLo = (am_dw == 1);                     // we==0 edge (k2<=2)
    bool e3  = (am_dw == 1) && (g == 0);         // k2==3
    bool e24 = (am_dw == 0) && (g == 1);         // k2==24
    bool eHi = (am_dw == 0);                     // we==7 edge (k2>=25)

    float2 xr[9];
    {   // prologue: A' table + zero range into LDS; preload x(se=0)
        const uint4* asrc = (const uint4*)A1;
        uint4* adst = (uint4*)(lds + C1_AOFF);
        #pragma unroll
        for (int i = 0; i < 7; ++i) {
            int q = tid + 256 * i;
            if (q < 1715) adst[q] = asrc[q];
        }
        #pragma unroll
        for (int i = 0; i < 5; ++i) {
            int q = tid + 256 * i;
            if (q < 1084) lds[C1_ZOFF + q] = 0u;
        }
        if (stager) {
            const float2* src = (const float2*)(xbase + (3 * OH) * 5832 + iw * 324 + id18 * 18);
            #pragma unroll
            for (int q = 0; q < 9; ++q) xr[q] = src[q];
        }
    }

    for (int se = 0; se < 9; ++se) {
        int kh = se - am_dh;
        int aoff = (kh >= 0 && kh < 7) ? (C1_AOFF + kh * 980 + alane) : C1_ZOFF;

        __syncthreads();                         // prior compute done (covers prologue at se=0)
        if (stager) {
            _Float16 h[19];
            #pragma unroll
            for (int q = 0; q < 9; ++q) { h[2*q] = (_Float16)xr[q].x; h[2*q+1] = (_Float16)xr[q].y; }
            h[18] = (_Float16)0.f;
            u32 e[9], o[9];
            #pragma unroll
            for (int q = 0; q < 9; ++q) e[q] = pack2(h[2*q], h[2*q+1]);
            #pragma unroll
            for (int q = 0; q < 9; ++q) o[q] = pack2(h[2*q+1], (q < 8) ? h[2*q+2] : h[18]);
            int base = tid * 52;
            #pragma unroll
            for (int ot = 0; ot < 12; ++ot) {
                uint4 w;
                if ((ot & 1) == 0) { const int q = ot >> 1;   w = (uint4){e[q], e[q+1], e[q+2], e[q+3]}; }
                else               { const int q = (ot-1)>>1; w = (uint4){o[q], o[q+1], o[q+2], o[q+3]}; }
                *(uint4*)(&lds[base + ot * 4]) = w;
            }
        }
        __syncthreads();

        if (se < 8 && stager) {                  // prefetch next stage into regs
            const float2* src = (const float2*)(xbase + (3 * OH + se + 1) * 5832 + iw * 324 + id18 * 18);
            #pragma unroll
            for (int q = 0; q < 9; ++q) xr[q] = src[q];
        }

        #pragma unroll
        for (int k2 = 0; k2 < 28; ++k2) {
            const int t0 = 2 * k2, t1 = 2 * k2 + 1;
            const int c0 = ((t0 / 7) * 18 + (t0 % 7)) * 52;
            const int c1 = ((t1 / 7) * 18 + (t1 % 7)) * 52;
            int qoff = g ? c1 : c0;
            int ao;
            if (k2 <= 2)       ao = eLo ? C1_ZOFF : aoff;
            else if (k2 == 3)  ao = e3  ? C1_ZOFF : aoff;
            else if (k2 == 24) ao = e24 ? C1_ZOFF : aoff;
            else if (k2 >= 25) ao = eHi ? C1_ZOFF : aoff;
            else               ao = aoff;
            f16x8 af = *(const f16x8*)(lds + ao + 40 * k2);
            f16x8 bf0 = *(const f16x8*)(lds + qn[0] + qoff);
            f16x8 bf1 = *(const f16x8*)(lds + qn[1] + qoff);
            acc0 = __builtin_amdgcn_mfma_f32_32x32x16_f16(af, bf0, acc0, 0, 0, 0);
            acc1 = __builtin_amdgcn_mfma_f32_32x32x16_f16(af, bf1, acc1, 0, 0, 0);
            if (wave == 0) {
                f16x8 bf2 = *(const f16x8*)(lds + qn[2] + qoff);
                acc2 = __builtin_amdgcn_mfma_f32_32x32x16_f16(af, bf2, acc2, 0, 0, 0);
            }
        }
    }

    // store: C row = (r&3)+8*(r>>2)+4*g -> m = dw*15+dh*5+oc; col -> (u,od,ot)
    #pragma unroll
    for (int s = 0; s < 3; ++s) {
        if (s == 2 && wave != 0) continue;
        f32x16 a = (s == 0) ? acc0 : ((s == 1) ? acc1 : acc2);
        int ow_b = 4 * OWp + 2 * u_[s];
        #pragma unroll
        for (int r = 0; r < 16; ++r) {
            const int m0 = (r & 3) + 8 * (r >> 2);
            const int m1 = m0 + 4;
            const int dw0 = m0 / 15, dh0 = (m0 % 15) / 5, oc0 = m0 % 5;
            const int dw1 = m1 / 15, dh1 = (m1 % 15) / 5, oc1 = m1 % 5;
            if (m1 >= 30 && g) continue;
            int dw = g ? dw1 : dw0;
            int dh = g ? dh1 : dh0;
            int oc = g ? oc1 : oc0;
            float bv = g ? b1[oc1] : b1[oc0];
            float v = fmaxf(a[r] + bv, 0.f);
            h1[(size_t)b * 103680 + oc * 20736 + (3 * OH + dh) * 1728
               + (ow_b + dw) * 144 + od_[s] * 12 + ot_[s]] = (_Float16)v;
        }
    }
}

// ---------------- conv2: 32x32x16 MFMA, windowed LDS, ci-split ----------------
// block=(b,OH2,ci): M=30=(dh3,oc10), N=216 -> 7 nt, K = 9 she x 25 k2.
#define C2_SLAB 4032
#define C2_ALDS 6400
__global__ __launch_bounds__(256, 3) void conv2_mfma(
    const _Float16* __restrict__ h1, const _Float16* __restrict__ A2,
    _Float16* __restrict__ part)
{
    __shared__ u32 lds[C2_SLAB + C2_ALDS];       // 41.7 KB
    int tid = threadIdx.x;
    int lane = tid & 63;
    int wave = tid >> 6;
    int col = lane & 31;
    int g = lane >> 5;

    int bid = (int)blockIdx.x;                   // 1280 = 8*160
    int lbid = (bid & 7) * 160 + (bid >> 3);
    int ci = lbid % 5;
    int OH2 = (lbid / 5) & 1;
    int b = lbid / 10;

    int qn[2], n_[2];
    #pragma unroll
    for (int s = 0; s < 2; ++s) {
        int nt = wave + 4 * s;
        int n = nt * 32 + col;                   // nt<=6 -> n<224
        n_[s] = n;
        int nc = (n < 216) ? n : 215;
        int ow = nc / 36, rem = nc % 36;
        int od = rem / 6, ot = rem % 6;
        qn[s] = (ow * 12 + od) * 28 + ot * 4;
    }

    f32x16 acc0, acc1;
    #pragma unroll
    for (int q = 0; q < 16; ++q) { acc0[q] = 0.f; acc1[q] = 0.f; }

    const _Float16* hbase = h1 + (size_t)b * 103680 + ci * 20736;
    const uint4* a2u = (const uint4*)(A2 + ((size_t)ci * 9) * 12800);
    int iw = tid / 12, id12 = tid % 12;
    bool stager = (tid < 144);

    uint2 xr[3]; uint4 apf[7];
    {
        if (stager) {
            const uint2* src = (const uint2*)(hbase + (3 * OH2) * 1728 + iw * 144 + id12 * 12);
            #pragma unroll
            for (int q = 0; q < 3; ++q) xr[q] = src[q];
        }
        #pragma unroll
        for (int i = 0; i < 7; ++i) { int q = tid + 256 * i; if (q < 1600) apf[i] = a2u[q]; }
    }

    for (int she = 0; she < 9; ++she) {
        __syncthreads();
        if (stager) {
            _Float16 h[14];
            *(uint2*)&h[0] = xr[0]; *(uint2*)&h[4] = xr[1]; *(uint2*)&h[8] = xr[2];
            h[12] = (_Float16)0.f;
            u32 e[6], o[6];
            #pragma unroll
            for (int q = 0; q < 6; ++q) e[q] = pack2(h[2*q], h[2*q+1]);
            #pragma unroll
            for (int q = 0; q < 6; ++q) o[q] = pack2(h[2*q+1], (q < 5) ? h[2*q+2] : h[12]);
            int base = tid * 28;
            #pragma unroll
            for (int ot = 0; ot < 6; ++ot) {
                uint4 w;
                if ((ot & 1) == 0) { const int q = ot >> 1;   w = (uint4){e[q], e[q+1], e[q+2], e[q+3]}; }
                else               { const int q = (ot-1)>>1; w = (uint4){o[q], o[q+1], o[q+2], o[q+3]}; }
                *(uint4*)(&lds[base + ot * 4]) = w;
            }
        }
        {
            uint4* adst = (uint4*)(&lds[C2_SLAB]);
            #pragma unroll
            for (int i = 0; i < 7; ++i) { int q = tid + 256 * i; if (q < 1600) adst[q] = apf[i]; }
        }
        __syncthreads();

        if (she < 8) {
            if (stager) {
                const uint2* src = (const uint2*)(hbase + (3 * OH2 + she + 1) * 1728 + iw * 144 + id12 * 12);
                #pragma unroll
                for (int q = 0; q < 3; ++q) xr[q] = src[q];
            }
            const uint4* asrc = a2u + (size_t)(she + 1) * 1600;
            #pragma unroll
            for (int i = 0; i < 7; ++i) { int q = tid + 256 * i; if (q < 1600) apf[i] = asrc[q]; }
        }

        const u32* alds = &lds[C2_SLAB];
        #pragma unroll
        for (int k2 = 0; k2 < 25; ++k2) {
            const int t0 = 2 * k2, t1 = 2 * k2 + 1;
            const int c0 = ((t0 / 7) * 12 + (t0 % 7)) * 28;
            const int c1 = (t1 < 49) ? ((t1 / 7) * 12 + (t1 % 7)) * 28 : 0;
            int qoff = g ? c1 : c0;
            f16x8 af = *(const f16x8*)(alds + (k2 * 64 + lane) * 4);
            f16x8 bf0 = *(const f16x8*)(lds + qn[0] + qoff);
            acc0 = __builtin_amdgcn_mfma_f32_32x32x16_f16(af, bf0, acc0, 0, 0, 0);
            if (wave < 3) {
                f16x8 bf1 = *(const f16x8*)(lds + qn[1] + qoff);
                acc1 = __builtin_amdgcn_mfma_f32_32x32x16_f16(af, bf1, acc1, 0, 0, 0);
            }
        }
    }

    // store partials: part[ci][b*6+oh][oc][216]; m = dh*10+oc
    #pragma unroll
    for (int s = 0; s < 2; ++s) {
        if (s == 1 && wave >= 3) continue;
        if (n_[s] >= 216) continue;
        f32x16 a = (s == 0) ? acc0 : acc1;
        #pragma unroll
        for (int r = 0; r < 16; ++r) {
            const int m0 = (r & 3) + 8 * (r >> 2);
            const int m1 = m0 + 4;
            const int dh0 = m0 / 10, oc0 = m0 % 10;
            const int dh1 = m1 / 10, oc1 = m1 % 10;
            if (m1 >= 30 && g) continue;
            int dh = g ? dh1 : dh0;
            int oc = g ? oc1 : oc0;
            int oh = 3 * OH2 + dh;
            part[((size_t)(ci * 768 + b * 6 + oh) * 10 + oc) * 216 + n_[s]] = (_Float16)a[r];
        }
    }
}

// ---------------- reduce 5 ci-partials + bias + ReLU -> h2 ----------------
__global__ __launch_bounds__(256) void conv2_reduce(
    const _Float16* __restrict__ part, const float* __restrict__ b2,
    _Float16* __restrict__ h2)
{
    int flat = blockIdx.x * 256 + threadIdx.x;   // 1,658,880 exact
    int n_loc = flat % 216;
    int t = flat / 216;
    int oc = t % 10;  t /= 10;
    int oh = t % 6;
    int b  = t / 6;
    float s = 0.f;
    #pragma unroll
    for (int ci = 0; ci < 5; ++ci)
        s += (float)part[((size_t)(ci * 768 + b * 6 + oh) * 10 + oc) * 216 + n_loc];
    s = fmaxf(s + b2[oc], 0.f);
    h2[(size_t)b * 12960 + oc * 1296 + oh * 216 + n_loc] = (_Float16)s;
}

// ---------------- linear + sigmoid ----------------
__global__ __launch_bounds__(256) void linear_kernel(
    const _Float16* __restrict__ h2, const float* __restrict__ wl,
    const float* __restrict__ bl, float* __restrict__ out)
{
    int b = blockIdx.x;
    const _Float16* hb = h2 + (size_t)b * 12960;
    float s = 0.f;
    for (int i = threadIdx.x; i < 12960; i += 256)
        s += (float)hb[i] * wl[i];
    #pragma unroll
    for (int off = 32; off > 0; off >>= 1)
        s += __shfl_down(s, off, 64);
    __shared__ float wsum[4];
    int wave = threadIdx.x >> 6;
    if ((threadIdx.x & 63) == 0) wsum[wave] = s;
    __syncthreads();
    if (threadIdx.x == 0) {
        float tot = wsum[0] + wsum[1] + wsum[2] + wsum[3] + bl[0];
        out[b] = 1.f / (1.f + expf(-tot));
    }
}

extern "C" void kernel_launch(void* const* d_in, const int* in_sizes, int n_in,
                              void* d_out, int out_size, void* d_ws, size_t ws_size,
                              hipStream_t stream) {
    const float* x  = (const float*)d_in[0];
    const float* w1 = (const float*)d_in[1];
    const float* b1 = (const float*)d_in[2];
    const float* w2 = (const float*)d_in[3];
    const float* b2 = (const float*)d_in[4];
    const float* wl = (const float*)d_in[5];
    const float* bl = (const float*)d_in[6];
    float* out = (float*)d_out;

    _Float16* h1   = (_Float16*)d_ws;            // 13,271,040
    _Float16* A1   = h1 + 13271040;              //    129,024 (13,720 used)
    _Float16* A2   = A1 + 129024;                //    576,000
    _Float16* part = A2 + 576000;                //  8,294,400
    _Float16* h2   = part + 8294400;             //  1,658,880

    pack_A1p<<<54, 256, 0, stream>>>(w1, A1);
    pack_A2v2<<<2250, 256, 0, stream>>>(w2, A2);
    conv1_mfma<<<1536, 256, 0, stream>>>(x, A1, b1, h1);
    conv2_mfma<<<1280, 256, 0, stream>>>(h1, A2, part);
    conv2_reduce<<<6480, 256, 0, stream>>>(part, b2, h2);
    linear_kernel<<<128, 256, 0, stream>>>(h2, wl, bl, out);
}

// Round 5
// 286.958 us; speedup vs baseline: 1.3793x; 1.1159x over previous
//
#include <hip/hip_runtime.h>
#include <math.h>

typedef unsigned u32;
typedef _Float16 f16x8 __attribute__((ext_vector_type(8)));
typedef float    f32x16 __attribute__((ext_vector_type(16)));

static __device__ __forceinline__ u32 pack2(_Float16 a, _Float16 b) {
    union { _Float16 h[2]; u32 u; } v;
    v.h[0] = a; v.h[1] = b;
    return v.u;
}

// ws (halves): h1 13,271,040 | A1 129,024 (19,200 used) | A2 576,000 | part 8,294,400 | h2 1,658,880

// ---------------- A-pack: bank-padded gather table ----------------
// A1'[kh8][kw7][kd7][oc5][j8] with padded strides (u32 units):
//   oc: 4, kd: 20, kw: 164 (140+24 pad), kh: 1164 (1148+16 pad)  -> addr ≡ 4m (mod 32)
//   kh=7 row + all pads = zeros (zero slot for invalid taps). Total 9600 u32.
__global__ __launch_bounds__(256) void pack_A1p(
    const float* __restrict__ w1, _Float16* __restrict__ A1)
{
    int i = blockIdx.x * 256 + threadIdx.x;      // u32 index, 9600 total (38 blocks)
    if (i >= 9600) return;
    u32 outv = 0u;
    int kh = i / 1164, r = i % 1164;
    if (kh < 7 && r < 1148) {
        int kw = r / 164, r2 = r % 164;
        if (r2 < 140) {
            int kd = r2 / 20, r3 = r2 % 20;
            int oc = r3 / 4, j2 = r3 % 4;
            int j0 = 2 * j2, j1 = 2 * j2 + 1;
            const float* wb = w1 + oc * 2401 + kh * 343 + kw * 49 + kd * 7;
            _Float16 v0 = (j0 < 7) ? (_Float16)wb[j0] : (_Float16)0.f;
            _Float16 v1 = (j1 < 7) ? (_Float16)wb[j1] : (_Float16)0.f;
            outv = pack2(v0, v1);
        }
    }
    ((u32*)A1)[i] = outv;
}

// ---------------- A-pack: A2[ci5][she9][k2 25][lane64][j8] ----------------
__global__ __launch_bounds__(256) void pack_A2v2(
    const float* __restrict__ w2, _Float16* __restrict__ A2)
{
    int i = blockIdx.x * 256 + threadIdx.x;      // 576000 exact
    int j = i & 7;
    int lane = (i >> 3) & 63;
    int t = i >> 9;
    int k2 = t % 25; t /= 25;
    int she = t % 9;
    int ci = t / 9;                              // 0..4
    int g = lane >> 5, m = lane & 31;
    int tap = 2 * k2 + g;                        // 0..49
    float v = 0.f;
    if (m < 30 && tap < 49 && j < 7) {
        int dh = m / 10, oc = m % 10;
        int kh = she - dh;
        if (kh >= 0 && kh < 7) {
            int kw = tap / 7, kd = tap % 7;
            v = w2[oc * 12005 + ci * 2401 + kh * 343 + kw * 49 + kd * 7 + j];
        }
    }
    A2[i] = (_Float16)v;
}

// ---------------- conv1: 32x32x16 MFMA, windowed LDS, 4 waves ----------------
// block=(b,OH,OWp): M=30=(dw2,dh3,oc5), N=288=(u2,od12,ot12) -> 9 nt,
// K = 9 se x 28 k2(2 taps x kt8). slab row stride 52 dw.
// A via persistent bank-padded LDS gather table (see pack_A1p):
//   lane addr = AOFF + kh*1164 + 4oc - 164dw + (164we + 20kd)   [we,kd compile-time per (k2,g)]
//   addr ≡ 4m + const (mod 32) -> conflict-free gather.
//   invalid kh/kw -> zero slot at kh=7 (+164 bias keeps dw=1 offsets in zeros).
//   junk lanes (col>=30): clamp m to 29, +4*(col-29) keeps the bank pattern.
#define C1_SLAB 9360
#define C1_AOFF 9360
#define C1_LDS  (9360 + 9600)                    // 75.84 KB
__global__ __launch_bounds__(256, 2) void conv1_mfma(
    const float* __restrict__ x, const _Float16* __restrict__ A1,
    const float* __restrict__ b1, _Float16* __restrict__ h1)
{
    __shared__ u32 lds[C1_LDS];
    int tid = threadIdx.x;
    int lane = tid & 63;
    int wave = tid >> 6;
    int col = lane & 31;
    int g = lane >> 5;

    int bid = (int)blockIdx.x;                   // 1536 = 8*192
    int lbid = (bid & 7) * 192 + (bid >> 3);     // XCD chunk swizzle
    int OWp = lbid % 3;
    int OH = (lbid / 3) & 3;
    int b = lbid / 12;

    int qn[3], u_[3], od_[3], ot_[3];
    #pragma unroll
    for (int s = 0; s < 3; ++s) {
        int nt = wave + 4 * s;
        int n = (nt <= 8) ? nt * 32 + col : col;
        int u = n / 144, r2 = n % 144;
        int od = r2 / 12, ot = r2 % 12;
        u_[s] = u; od_[s] = od; ot_[s] = ot;
        qn[s] = (u * 36 + od) * 52 + ot * 4;
    }

    f32x16 acc0, acc1, acc2;
    #pragma unroll
    for (int q = 0; q < 16; ++q) { acc0[q] = 0.f; acc1[q] = 0.f; acc2[q] = 0.f; }

    const float* xbase = x + (size_t)b * 104976;
    int w10 = tid / 18, id18 = tid % 18;
    int iw = 4 * OWp + w10;
    bool stager = (tid < 180);

    // lane A-gather constants (bank-perfect layout)
    int mc = (col < 30) ? col : 29;
    int am_dw = mc / 15, am_dh = (mc % 15) / 5, am_oc = mc % 5;
    int jadd = 4 * (col - mc);                   // 0; 4/8 for col 30/31
    int vlane = 4 * am_oc - 164 * am_dw + jadd;
    int zbase = C1_AOFF + 8312 + vlane;          // zero slot (kh=7 +164 bias)
    bool eLo = (am_dw == 1);                     // we==0 edge (k2<=2)
    bool e3  = (am_dw == 1) && (g == 0);         // k2==3, tap0 we==0
    bool e24 = (am_dw == 0) && (g == 1);         // k2==24, tap1 we==7
    bool eHi = (am_dw == 0);                     // we==7 edge (k2>=25)

    float2 xr[9];
    {   // prologue: A' table into LDS; preload x(se=0)
        const uint4* asrc = (const uint4*)A1;
        uint4* adst = (uint4*)(lds + C1_AOFF);
        #pragma unroll
        for (int i = 0; i < 10; ++i) {
            int q = tid + 256 * i;
            if (q < 2400) adst[q] = asrc[q];
        }
        if (stager) {
            const float2* src = (const float2*)(xbase + (3 * OH) * 5832 + iw * 324 + id18 * 18);
            #pragma unroll
            for (int q = 0; q < 9; ++q) xr[q] = src[q];
        }
    }

    for (int se = 0; se < 9; ++se) {
        int kh = se - am_dh;
        int vbase = (kh >= 0 && kh < 7) ? (C1_AOFF + kh * 1164 + vlane) : zbase;

        __syncthreads();                         // prior compute done (covers prologue at se=0)
        if (stager) {
            _Float16 h[19];
            #pragma unroll
            for (int q = 0; q < 9; ++q) { h[2*q] = (_Float16)xr[q].x; h[2*q+1] = (_Float16)xr[q].y; }
            h[18] = (_Float16)0.f;
            u32 e[9], o[9];
            #pragma unroll
            for (int q = 0; q < 9; ++q) e[q] = pack2(h[2*q], h[2*q+1]);
            #pragma unroll
            for (int q = 0; q < 9; ++q) o[q] = pack2(h[2*q+1], (q < 8) ? h[2*q+2] : h[18]);
            int base = tid * 52;
            #pragma unroll
            for (int ot = 0; ot < 12; ++ot) {
                uint4 w;
                if ((ot & 1) == 0) { const int q = ot >> 1;   w = (uint4){e[q], e[q+1], e[q+2], e[q+3]}; }
                else               { const int q = (ot-1)>>1; w = (uint4){o[q], o[q+1], o[q+2], o[q+3]}; }
                *(uint4*)(&lds[base + ot * 4]) = w;
            }
        }
        __syncthreads();

        if (se < 8 && stager) {                  // prefetch next stage into regs
            const float2* src = (const float2*)(xbase + (3 * OH + se + 1) * 5832 + iw * 324 + id18 * 18);
            #pragma unroll
            for (int q = 0; q < 9; ++q) xr[q] = src[q];
        }

        #pragma unroll
        for (int k2 = 0; k2 < 28; ++k2) {
            const int t0 = 2 * k2, t1 = 2 * k2 + 1;
            const int c0 = ((t0 / 7) * 18 + (t0 % 7)) * 52;
            const int c1 = ((t1 / 7) * 18 + (t1 % 7)) * 52;
            const int ca0 = 164 * (t0 / 7) + 20 * (t0 % 7);
            const int ca1 = 164 * (t1 / 7) + 20 * (t1 % 7);
            int qoff = g ? c1 : c0;
            int ca   = g ? ca1 : ca0;
            int abase;
            if (k2 <= 2)       abase = eLo ? zbase : vbase;
            else if (k2 == 3)  abase = e3  ? zbase : vbase;
            else if (k2 == 24) abase = e24 ? zbase : vbase;
            else if (k2 >= 25) abase = eHi ? zbase : vbase;
            else               abase = vbase;
            f16x8 af = *(const f16x8*)(lds + abase + ca);
            f16x8 bf0 = *(const f16x8*)(lds + qn[0] + qoff);
            f16x8 bf1 = *(const f16x8*)(lds + qn[1] + qoff);
            acc0 = __builtin_amdgcn_mfma_f32_32x32x16_f16(af, bf0, acc0, 0, 0, 0);
            acc1 = __builtin_amdgcn_mfma_f32_32x32x16_f16(af, bf1, acc1, 0, 0, 0);
            if (wave == 0) {
                f16x8 bf2 = *(const f16x8*)(lds + qn[2] + qoff);
                acc2 = __builtin_amdgcn_mfma_f32_32x32x16_f16(af, bf2, acc2, 0, 0, 0);
            }
        }
    }

    // store: C row = (r&3)+8*(r>>2)+4*g -> m = dw*15+dh*5+oc; col -> (u,od,ot)
    #pragma unroll
    for (int s = 0; s < 3; ++s) {
        if (s == 2 && wave != 0) continue;
        f32x16 a = (s == 0) ? acc0 : ((s == 1) ? acc1 : acc2);
        int ow_b = 4 * OWp + 2 * u_[s];
        #pragma unroll
        for (int r = 0; r < 16; ++r) {
            const int m0 = (r & 3) + 8 * (r >> 2);
            const int m1 = m0 + 4;
            const int dw0 = m0 / 15, dh0 = (m0 % 15) / 5, oc0 = m0 % 5;
            const int dw1 = m1 / 15, dh1 = (m1 % 15) / 5, oc1 = m1 % 5;
            if (m1 >= 30 && g) continue;
            int dw = g ? dw1 : dw0;
            int dh = g ? dh1 : dh0;
            int oc = g ? oc1 : oc0;
            float bv = g ? b1[oc1] : b1[oc0];
            float v = fmaxf(a[r] + bv, 0.f);
            h1[(size_t)b * 103680 + oc * 20736 + (3 * OH + dh) * 1728
               + (ow_b + dw) * 144 + od_[s] * 12 + ot_[s]] = (_Float16)v;
        }
    }
}

// ---------------- conv2: 32x32x16 MFMA, windowed LDS, ci-split ----------------
// block=(b,OH2,ci): M=30=(dh3,oc10), N=216 -> 7 nt, K = 9 she x 25 k2.
#define C2_SLAB 4032
#define C2_ALDS 6400
__global__ __launch_bounds__(256, 3) void conv2_mfma(
    const _Float16* __restrict__ h1, const _Float16* __restrict__ A2,
    _Float16* __restrict__ part)
{
    __shared__ u32 lds[C2_SLAB + C2_ALDS];       // 41.7 KB
    int tid = threadIdx.x;
    int lane = tid & 63;
    int wave = tid >> 6;
    int col = lane & 31;
    int g = lane >> 5;

    int bid = (int)blockIdx.x;                   // 1280 = 8*160
    int lbid = (bid & 7) * 160 + (bid >> 3);
    int ci = lbid % 5;
    int OH2 = (lbid / 5) & 1;
    int b = lbid / 10;

    int qn[2], n_[2];
    #pragma unroll
    for (int s = 0; s < 2; ++s) {
        int nt = wave + 4 * s;
        int n = nt * 32 + col;                   // nt<=6 -> n<224
        n_[s] = n;
        int nc = (n < 216) ? n : 215;
        int ow = nc / 36, rem = nc % 36;
        int od = rem / 6, ot = rem % 6;
        qn[s] = (ow * 12 + od) * 28 + ot * 4;
    }

    f32x16 acc0, acc1;
    #pragma unroll
    for (int q = 0; q < 16; ++q) { acc0[q] = 0.f; acc1[q] = 0.f; }

    const _Float16* hbase = h1 + (size_t)b * 103680 + ci * 20736;
    const uint4* a2u = (const uint4*)(A2 + ((size_t)ci * 9) * 12800);
    int iw = tid / 12, id12 = tid % 12;
    bool stager = (tid < 144);

    uint2 xr[3]; uint4 apf[7];
    {
        if (stager) {
            const uint2* src = (const uint2*)(hbase + (3 * OH2) * 1728 + iw * 144 + id12 * 12);
            #pragma unroll
            for (int q = 0; q < 3; ++q) xr[q] = src[q];
        }
        #pragma unroll
        for (int i = 0; i < 7; ++i) { int q = tid + 256 * i; if (q < 1600) apf[i] = a2u[q]; }
    }

    for (int she = 0; she < 9; ++she) {
        __syncthreads();
        if (stager) {
            _Float16 h[14];
            *(uint2*)&h[0] = xr[0]; *(uint2*)&h[4] = xr[1]; *(uint2*)&h[8] = xr[2];
            h[12] = (_Float16)0.f;
            u32 e[6], o[6];
            #pragma unroll
            for (int q = 0; q < 6; ++q) e[q] = pack2(h[2*q], h[2*q+1]);
            #pragma unroll
            for (int q = 0; q < 6; ++q) o[q] = pack2(h[2*q+1], (q < 5) ? h[2*q+2] : h[12]);
            int base = tid * 28;
            #pragma unroll
            for (int ot = 0; ot < 6; ++ot) {
                uint4 w;
                if ((ot & 1) == 0) { const int q = ot >> 1;   w = (uint4){e[q], e[q+1], e[q+2], e[q+3]}; }
                else               { const int q = (ot-1)>>1; w = (uint4){o[q], o[q+1], o[q+2], o[q+3]}; }
                *(uint4*)(&lds[base + ot * 4]) = w;
            }
        }
        {
            uint4* adst = (uint4*)(&lds[C2_SLAB]);
            #pragma unroll
            for (int i = 0; i < 7; ++i) { int q = tid + 256 * i; if (q < 1600) adst[q] = apf[i]; }
        }
        __syncthreads();

        if (she < 8) {
            if (stager) {
                const uint2* src = (const uint2*)(hbase + (3 * OH2 + she + 1) * 1728 + iw * 144 + id12 * 12);
                #pragma unroll
                for (int q = 0; q < 3; ++q) xr[q] = src[q];
            }
            const uint4* asrc = a2u + (size_t)(she + 1) * 1600;
            #pragma unroll
            for (int i = 0; i < 7; ++i) { int q = tid + 256 * i; if (q < 1600) apf[i] = asrc[q]; }
        }

        const u32* alds = &lds[C2_SLAB];
        #pragma unroll
        for (int k2 = 0; k2 < 25; ++k2) {
            const int t0 = 2 * k2, t1 = 2 * k2 + 1;
            const int c0 = ((t0 / 7) * 12 + (t0 % 7)) * 28;
            const int c1 = (t1 < 49) ? ((t1 / 7) * 12 + (t1 % 7)) * 28 : 0;
            int qoff = g ? c1 : c0;
            f16x8 af = *(const f16x8*)(alds + (k2 * 64 + lane) * 4);
            f16x8 bf0 = *(const f16x8*)(lds + qn[0] + qoff);
            acc0 = __builtin_amdgcn_mfma_f32_32x32x16_f16(af, bf0, acc0, 0, 0, 0);
            if (wave < 3) {
                f16x8 bf1 = *(const f16x8*)(lds + qn[1] + qoff);
                acc1 = __builtin_amdgcn_mfma_f32_32x32x16_f16(af, bf1, acc1, 0, 0, 0);
            }
        }
    }

    // store partials: part[ci][b*6+oh][oc][216]; m = dh*10+oc
    #pragma unroll
    for (int s = 0; s < 2; ++s) {
        if (s == 1 && wave >= 3) continue;
        if (n_[s] >= 216) continue;
        f32x16 a = (s == 0) ? acc0 : acc1;
        #pragma unroll
        for (int r = 0; r < 16; ++r) {
            const int m0 = (r & 3) + 8 * (r >> 2);
            const int m1 = m0 + 4;
            const int dh0 = m0 / 10, oc0 = m0 % 10;
            const int dh1 = m1 / 10, oc1 = m1 % 10;
            if (m1 >= 30 && g) continue;
            int dh = g ? dh1 : dh0;
            int oc = g ? oc1 : oc0;
            int oh = 3 * OH2 + dh;
            part[((size_t)(ci * 768 + b * 6 + oh) * 10 + oc) * 216 + n_[s]] = (_Float16)a[r];
        }
    }
}

// ---------------- reduce 5 ci-partials + bias + ReLU -> h2 ----------------
__global__ __launch_bounds__(256) void conv2_reduce(
    const _Float16* __restrict__ part, const float* __restrict__ b2,
    _Float16* __restrict__ h2)
{
    int flat = blockIdx.x * 256 + threadIdx.x;   // 1,658,880 exact
    int n_loc = flat % 216;
    int t = flat / 216;
    int oc = t % 10;  t /= 10;
    int oh = t % 6;
    int b  = t / 6;
    float s = 0.f;
    #pragma unroll
    for (int ci = 0; ci < 5; ++ci)
        s += (float)part[((size_t)(ci * 768 + b * 6 + oh) * 10 + oc) * 216 + n_loc];
    s = fmaxf(s + b2[oc], 0.f);
    h2[(size_t)b * 12960 + oc * 1296 + oh * 216 + n_loc] = (_Float16)s;
}

// ---------------- linear + sigmoid ----------------
__global__ __launch_bounds__(256) void linear_kernel(
    const _Float16* __restrict__ h2, const float* __restrict__ wl,
    const float* __restrict__ bl, float* __restrict__ out)
{
    int b = blockIdx.x;
    const _Float16* hb = h2 + (size_t)b * 12960;
    float s = 0.f;
    for (int i = threadIdx.x; i < 12960; i += 256)
        s += (float)hb[i] * wl[i];
    #pragma unroll
    for (int off = 32; off > 0; off >>= 1)
        s += __shfl_down(s, off, 64);
    __shared__ float wsum[4];
    int wave = threadIdx.x >> 6;
    if ((threadIdx.x & 63) == 0) wsum[wave] = s;
    __syncthreads();
    if (threadIdx.x == 0) {
        float tot = wsum[0] + wsum[1] + wsum[2] + wsum[3] + bl[0];
        out[b] = 1.f / (1.f + expf(-tot));
    }
}

extern "C" void kernel_launch(void* const* d_in, const int* in_sizes, int n_in,
                              void* d_out, int out_size, void* d_ws, size_t ws_size,
                              hipStream_t stream) {
    const float* x  = (const float*)d_in[0];
    const float* w1 = (const float*)d_in[1];
    const float* b1 = (const float*)d_in[2];
    const float* w2 = (const float*)d_in[3];
    const float* b2 = (const float*)d_in[4];
    const float* wl = (const float*)d_in[5];
    const float* bl = (const float*)d_in[6];
    float* out = (float*)d_out;

    _Float16* h1   = (_Float16*)d_ws;            // 13,271,040
    _Float16* A1   = h1 + 13271040;              //    129,024 (19,200 used)
    _Float16* A2   = A1 + 129024;                //    576,000
    _Float16* part = A2 + 576000;                //  8,294,400
    _Float16* h2   = part + 8294400;             //  1,658,880

    pack_A1p<<<38, 256, 0, stream>>>(w1, A1);
    pack_A2v2<<<2250, 256, 0, stream>>>(w2, A2);
    conv1_mfma<<<1536, 256, 0, stream>>>(x, A1, b1, h1);
    conv2_mfma<<<1280, 256, 0, stream>>>(h1, A2, part);
    conv2_reduce<<<6480, 256, 0, stream>>>(part, b2, h2);
    linear_kernel<<<128, 256, 0, stream>>>(h2, wl, bl, out);
}